// Round 3
// baseline (270.307 us; speedup 1.0000x reference)
//
#include <hip/hip_runtime.h>
#include <math.h>

// Problem constants
#define NB 32
#define NC 64
#define NHW 3136          // 56*56
#define NM 6
#define NDIM 192
#define NHEADS 8
#define NINNER 512        // NHEADS*NC
#define NKV 3072          // NHEADS*NM*NC per batch
#define CHW (NC * NHW)    // 200704
#define PAD 65

// ---------------------------------------------------------------------------
// Kernel 1: kflat = flat(z@Wk+bk); VW[g][c] = sum_cc v[g*64+cc]*Wo[(h*64+cc)*64+c]
// grid (32,12) x 256. 2-way split accumulators for ILP (4 indep chains).
// ---------------------------------------------------------------------------
__global__ __launch_bounds__(256) void kv_proj_kernel(
    const float* __restrict__ z, const float* __restrict__ Wk,
    const float* __restrict__ bk, const float* __restrict__ Wv,
    const float* __restrict__ bv, const float* __restrict__ Wo,
    float* __restrict__ kflat, float* __restrict__ vw) {
  const int b = blockIdx.x;
  const int chunk = blockIdx.y;
  const int tid = threadIdx.x;
  const int idx = chunk * 256 + tid;   // 0..3071
  const int m = idx >> 9;              // uniform per block
  const int i = idx & 511;

  __shared__ float zs[NM * NDIM];
  __shared__ float vs[256];

  for (int t = tid; t < NM * NDIM; t += 256) zs[t] = z[b * (NM * NDIM) + t];
  __syncthreads();

  float ak0 = bk[i], ak1 = 0.f, av0 = bv[i], av1 = 0.f;
  const float* zr = zs + m * NDIM;
  #pragma unroll 8
  for (int d = 0; d < NDIM; d += 2) {
    const float z0 = zr[d], z1 = zr[d + 1];
    ak0 = fmaf(z0, Wk[d * NINNER + i], ak0);
    ak1 = fmaf(z1, Wk[(d + 1) * NINNER + i], ak1);
    av0 = fmaf(z0, Wv[d * NINNER + i], av0);
    av1 = fmaf(z1, Wv[(d + 1) * NINNER + i], av1);
  }
  kflat[b * NKV + idx] = ak0 + ak1;
  vs[tid] = av0 + av1;
  __syncthreads();

  const int gl = tid >> 6;             // 0..3 (uniform per wave)
  const int c = tid & 63;
  const int g = chunk * 4 + gl;        // 0..47
  const int h = g / 6;
  float a0 = 0.f, a1 = 0.f;
  #pragma unroll 8
  for (int cc = 0; cc < NC; cc += 2) {
    a0 = fmaf(vs[gl * 64 + cc],     Wo[(h * NC + cc) * NC + c],     a0);
    a1 = fmaf(vs[gl * 64 + cc + 1], Wo[(h * NC + cc + 1) * NC + c], a1);
  }
  vw[b * NKV + g * NC + c] = a0 + a1;
}

// ---------------------------------------------------------------------------
// Kernel 2: attention. grid (32,49), block 256 = 4 waves over the SAME 64
// rows; wave w handles heads {2w, 2w+1}. Partials combined via transposed
// LDS buffers (conflict-free writes), paired RMW reduce, float4 epilogue.
// ---------------------------------------------------------------------------
__global__ __launch_bounds__(256, 3) void attn_kernel(
    const float* __restrict__ x, const float* __restrict__ kflat,
    const float* __restrict__ vw, const float* __restrict__ bo,
    float* __restrict__ out) {
  const int b = blockIdx.x;
  const int lane = threadIdx.x & 63;
  const int w = threadIdx.x >> 6;
  const int n = blockIdx.y * 64 + lane;   // 0..3135 exact
  const float* __restrict__ xb = x + (size_t)b * CHW;

  __shared__ float buf[2][NC][PAD];       // ~32.5 KB

  // q[cc] = x[b, cc, n]  (stride-1 in n across the wave)
  float q[NC];
  #pragma unroll
  for (int cc = 0; cc < NC; ++cc) q[cc] = xb[(size_t)cc * NHW + n];

  const float* __restrict__ kb = kflat + b * NKV;
  const float* __restrict__ vb = vw + b * NKV;

  float o[NC];
  #pragma unroll
  for (int c = 0; c < NC; ++c) o[c] = 0.f;

  const float scale = 0.125f;  // 64^-0.5
  const int h0 = w * 2;

  #pragma unroll 1
  for (int hh = 0; hh < 2; ++hh) {
    const int h = h0 + hh;
    const float* kh = kb + h * (NM * NC);
    float d[NM];
    #pragma unroll
    for (int mm = 0; mm < NM; ++mm) {
      const float* km = kh + mm * NC;
      float a0 = 0.f, a1 = 0.f, a2 = 0.f, a3 = 0.f;
      #pragma unroll
      for (int cc = 0; cc < NC; cc += 4) {
        a0 = fmaf(q[cc + 0], km[cc + 0], a0);
        a1 = fmaf(q[cc + 1], km[cc + 1], a1);
        a2 = fmaf(q[cc + 2], km[cc + 2], a2);
        a3 = fmaf(q[cc + 3], km[cc + 3], a3);
      }
      d[mm] = (a0 + a1) + (a2 + a3);
    }
    float mx = d[0];
    #pragma unroll
    for (int mm = 1; mm < NM; ++mm) mx = fmaxf(mx, d[mm]);
    float e[NM];
    float s = 0.f;
    #pragma unroll
    for (int mm = 0; mm < NM; ++mm) {
      e[mm] = __expf((d[mm] - mx) * scale);
      s += e[mm];
    }
    const float r = 1.0f / s;
    const float* vh = vb + h * (NM * NC);
    #pragma unroll
    for (int mm = 0; mm < NM; ++mm) {
      const float a = e[mm] * r;
      const float* vm = vh + mm * NC;
      #pragma unroll
      for (int c = 0; c < NC; ++c) o[c] = fmaf(a, vm[c], o[c]);
    }
  }

  // ---- reduce 4 wave-partials: waves {0,2} write, {1,3} add ----
  const int half = w >> 1;
  if ((w & 1) == 0) {
    #pragma unroll
    for (int c = 0; c < NC; ++c) buf[half][c][lane] = o[c];
  }
  __syncthreads();
  if ((w & 1) == 1) {
    #pragma unroll
    for (int c = 0; c < NC; ++c) buf[half][c][lane] += o[c];
  }
  __syncthreads();

  // ---- epilogue: thread t -> row n2 = t>>2, 16 channels at c0=(t&3)*16 ----
  const int n2 = threadIdx.x >> 2;        // 0..63
  const int c0 = (threadIdx.x & 3) * 16;
  const size_t base = (size_t)(blockIdx.y * 64 + n2) * NC + c0;  // flat [n,c]
  const float4* __restrict__ xr = (const float4*)(xb + base);
  const float4* __restrict__ bo4 = (const float4*)(bo + c0);
  float4* __restrict__ op = (float4*)(out + (size_t)b * CHW + base);
  #pragma unroll
  for (int j = 0; j < 4; ++j) {
    const float4 xv = xr[j];
    const float4 bv4 = bo4[j];
    float4 rr;
    rr.x = buf[0][c0 + 4*j + 0][n2] + buf[1][c0 + 4*j + 0][n2] + bv4.x + xv.x;
    rr.y = buf[0][c0 + 4*j + 1][n2] + buf[1][c0 + 4*j + 1][n2] + bv4.y + xv.y;
    rr.z = buf[0][c0 + 4*j + 2][n2] + buf[1][c0 + 4*j + 2][n2] + bv4.z + xv.z;
    rr.w = buf[0][c0 + 4*j + 3][n2] + buf[1][c0 + 4*j + 3][n2] + bv4.w + xv.w;
    op[j] = rr;
  }
}

extern "C" void kernel_launch(void* const* d_in, const int* in_sizes, int n_in,
                              void* d_out, int out_size, void* d_ws, size_t ws_size,
                              hipStream_t stream) {
  const float* x  = (const float*)d_in[0];
  const float* z  = (const float*)d_in[1];
  const float* Wk = (const float*)d_in[2];
  const float* bk = (const float*)d_in[3];
  const float* Wv = (const float*)d_in[4];
  const float* bv = (const float*)d_in[5];
  const float* Wo = (const float*)d_in[6];
  const float* bo = (const float*)d_in[7];
  float* out = (float*)d_out;

  float* ws = (float*)d_ws;
  float* kflat = ws;                 // NB*NKV floats
  float* vw    = ws + NB * NKV;      // NB*NKV floats

  kv_proj_kernel<<<dim3(NB, 12), 256, 0, stream>>>(z, Wk, bk, Wv, bv, Wo,
                                                   kflat, vw);
  attn_kernel<<<dim3(NB, 49), 256, 0, stream>>>(x, kflat, vw, bo, out);
}

// Round 4
// 181.542 us; speedup vs baseline: 1.4889x; 1.4889x over previous
//
#include <hip/hip_runtime.h>
#include <math.h>

// Problem constants
#define NB 32
#define NC 64
#define NHW 3136          // 56*56
#define NM 6
#define NDIM 192
#define NHEADS 8
#define NINNER 512        // NHEADS*NC
#define NKV 3072          // NHEADS*NM*NC per batch
#define CHW (NC * NHW)    // 200704
#define NG 48             // NHEADS*NM

// ---------------------------------------------------------------------------
// Kernel 1: kflat = flat(z@Wk+bk); VW[g][c] = sum_cc v[g*64+cc]*Wo[(h*64+cc)*64+c]
// grid (32,12) x 256.
// ---------------------------------------------------------------------------
__global__ __launch_bounds__(256) void kv_proj_kernel(
    const float* __restrict__ z, const float* __restrict__ Wk,
    const float* __restrict__ bk, const float* __restrict__ Wv,
    const float* __restrict__ bv, const float* __restrict__ Wo,
    float* __restrict__ kflat, float* __restrict__ vw) {
  const int b = blockIdx.x;
  const int chunk = blockIdx.y;
  const int tid = threadIdx.x;
  const int idx = chunk * 256 + tid;   // 0..3071
  const int m = idx >> 9;              // uniform per block
  const int i = idx & 511;

  __shared__ float zs[NM * NDIM];
  __shared__ float vs[256];

  for (int t = tid; t < NM * NDIM; t += 256) zs[t] = z[b * (NM * NDIM) + t];
  __syncthreads();

  float ak0 = bk[i], ak1 = 0.f, av0 = bv[i], av1 = 0.f;
  const float* zr = zs + m * NDIM;
  #pragma unroll 8
  for (int d = 0; d < NDIM; d += 2) {
    const float z0 = zr[d], z1 = zr[d + 1];
    ak0 = fmaf(z0, Wk[d * NINNER + i], ak0);
    ak1 = fmaf(z1, Wk[(d + 1) * NINNER + i], ak1);
    av0 = fmaf(z0, Wv[d * NINNER + i], av0);
    av1 = fmaf(z1, Wv[(d + 1) * NINNER + i], av1);
  }
  kflat[b * NKV + idx] = ak0 + ak1;
  vs[tid] = av0 + av1;
  __syncthreads();

  const int gl = tid >> 6;             // 0..3 (uniform per wave)
  const int c = tid & 63;
  const int g = chunk * 4 + gl;        // 0..47
  const int h = g / 6;
  float a0 = 0.f, a1 = 0.f;
  #pragma unroll 8
  for (int cc = 0; cc < NC; cc += 2) {
    a0 = fmaf(vs[gl * 64 + cc],     Wo[(h * NC + cc) * NC + c],     a0);
    a1 = fmaf(vs[gl * 64 + cc + 1], Wo[(h * NC + cc + 1) * NC + c], a1);
  }
  vw[b * NKV + g * NC + c] = a0 + a1;
}

// ---------------------------------------------------------------------------
// Kernel 2: attention, two-phase. grid (32,49), block 256 (4 waves, same 64
// rows). Phase 1: wave w computes dots+softmax for heads {2w,2w+1}, writes
// 48 attn weights per row to LDS. Phase 2: wave w computes output channels
// [16w,16w+16) over all 48 (h,m) -> o[16] per thread, no reduction.
// Per-thread state is tiny (no q[64]/o[64] arrays) -> no spill.
// ---------------------------------------------------------------------------
__global__ __launch_bounds__(256, 4) void attn_kernel(
    const float* __restrict__ x, const float* __restrict__ kflat,
    const float* __restrict__ vw, const float* __restrict__ bo,
    float* __restrict__ out) {
  const int b = blockIdx.x;
  const int lane = threadIdx.x & 63;
  const int w = threadIdx.x >> 6;
  const int n = blockIdx.y * 64 + lane;   // 0..3135 exact
  const float* __restrict__ xb = x + (size_t)b * CHW;

  __shared__ float qs[NC][64];   // [c][n_local], 16 KB, conflict-free
  __shared__ float aw[NG][64];   // [g][n_local], 12 KB, conflict-free

  // ---- stage q: wave w loads channels 16w..16w+15 (coalesced) ----
  #pragma unroll
  for (int j = 0; j < 16; ++j) {
    const int c = w * 16 + j;
    qs[c][lane] = xb[(size_t)c * NHW + n];
  }
  __syncthreads();

  // ---- phase 1: dots for heads 2w, 2w+1 ----
  const float* __restrict__ kb = kflat + b * NKV;
  const float* __restrict__ k0 = kb + (2 * w) * (NM * NC);
  const float* __restrict__ k1 = k0 + NM * NC;

  float d0[NM], d1[NM];
  #pragma unroll
  for (int mm = 0; mm < NM; ++mm) { d0[mm] = 0.f; d1[mm] = 0.f; }

  #pragma unroll 4
  for (int cc = 0; cc < NC; ++cc) {
    const float qv = qs[cc][lane];       // 1 ds_read, 12 FMAs
    #pragma unroll
    for (int mm = 0; mm < NM; ++mm) {
      d0[mm] = fmaf(qv, k0[mm * NC + cc], d0[mm]);
      d1[mm] = fmaf(qv, k1[mm * NC + cc], d1[mm]);
    }
  }

  const float scale = 0.125f;  // 64^-0.5
  {
    float mx = d0[0];
    #pragma unroll
    for (int mm = 1; mm < NM; ++mm) mx = fmaxf(mx, d0[mm]);
    float e[NM], s = 0.f;
    #pragma unroll
    for (int mm = 0; mm < NM; ++mm) { e[mm] = __expf((d0[mm] - mx) * scale); s += e[mm]; }
    const float r = 1.0f / s;
    #pragma unroll
    for (int mm = 0; mm < NM; ++mm) aw[(2 * w) * NM + mm][lane] = e[mm] * r;
  }
  {
    float mx = d1[0];
    #pragma unroll
    for (int mm = 1; mm < NM; ++mm) mx = fmaxf(mx, d1[mm]);
    float e[NM], s = 0.f;
    #pragma unroll
    for (int mm = 0; mm < NM; ++mm) { e[mm] = __expf((d1[mm] - mx) * scale); s += e[mm]; }
    const float r = 1.0f / s;
    #pragma unroll
    for (int mm = 0; mm < NM; ++mm) aw[(2 * w + 1) * NM + mm][lane] = e[mm] * r;
  }
  __syncthreads();

  // ---- phase 2: PV for channels c0..c0+15 over all 48 (h,m) ----
  const int c0 = w * 16;
  const float* __restrict__ vb = vw + b * NKV + c0;
  float o[16];
  #pragma unroll
  for (int j = 0; j < 16; ++j) o[j] = 0.f;

  #pragma unroll 2
  for (int g = 0; g < NG; ++g) {
    const float a = aw[g][lane];         // 1 ds_read, 16 FMAs
    const float* __restrict__ vg = vb + g * NC;
    #pragma unroll
    for (int j = 0; j < 16; ++j) o[j] = fmaf(a, vg[j], o[j]);
  }

  // ---- epilogue: per-lane 4x float4 with bias + residual ----
  const size_t base = (size_t)b * CHW + (size_t)n * NC + c0;
  const float4* __restrict__ xr = (const float4*)(x + base);
  const float4* __restrict__ bo4 = (const float4*)(bo + c0);
  float4* __restrict__ op = (float4*)(out + base);
  #pragma unroll
  for (int j = 0; j < 4; ++j) {
    const float4 xv = xr[j];
    const float4 bv4 = bo4[j];
    float4 rr;
    rr.x = o[4 * j + 0] + bv4.x + xv.x;
    rr.y = o[4 * j + 1] + bv4.y + xv.y;
    rr.z = o[4 * j + 2] + bv4.z + xv.z;
    rr.w = o[4 * j + 3] + bv4.w + xv.w;
    op[j] = rr;
  }
}

extern "C" void kernel_launch(void* const* d_in, const int* in_sizes, int n_in,
                              void* d_out, int out_size, void* d_ws, size_t ws_size,
                              hipStream_t stream) {
  const float* x  = (const float*)d_in[0];
  const float* z  = (const float*)d_in[1];
  const float* Wk = (const float*)d_in[2];
  const float* bk = (const float*)d_in[3];
  const float* Wv = (const float*)d_in[4];
  const float* bv = (const float*)d_in[5];
  const float* Wo = (const float*)d_in[6];
  const float* bo = (const float*)d_in[7];
  float* out = (float*)d_out;

  float* ws = (float*)d_ws;
  float* kflat = ws;                 // NB*NKV floats
  float* vw    = ws + NB * NKV;      // NB*NKV floats

  kv_proj_kernel<<<dim3(NB, 12), 256, 0, stream>>>(z, Wk, bk, Wv, bv, Wo,
                                                   kflat, vw);
  attn_kernel<<<dim3(NB, 49), 256, 0, stream>>>(x, kflat, vw, bo, out);
}

// Round 5
// 128.371 us; speedup vs baseline: 2.1057x; 1.4142x over previous
//
#include <hip/hip_runtime.h>
#include <math.h>

// Problem constants
#define NB 32
#define NC 64
#define NHW 3136          // 56*56
#define NM 6
#define NDIM 192
#define NHEADS 8
#define NINNER 512        // NHEADS*NC
#define NKV 3072          // NHEADS*NM*NC per batch
#define CHW (NC * NHW)    // 200704
#define NG 48             // NHEADS*NM

// ---------------------------------------------------------------------------
// Kernel 1: kflat = flat(z@Wk+bk); VW[g][c] = sum_cc v[g*64+cc]*Wo[(h*64+cc)*64+c]
// grid (32,12) x 256.
// ---------------------------------------------------------------------------
__global__ __launch_bounds__(256) void kv_proj_kernel(
    const float* __restrict__ z, const float* __restrict__ Wk,
    const float* __restrict__ bk, const float* __restrict__ Wv,
    const float* __restrict__ bv, const float* __restrict__ Wo,
    float* __restrict__ kflat, float* __restrict__ vw) {
  const int b = blockIdx.x;
  const int chunk = blockIdx.y;
  const int tid = threadIdx.x;
  const int idx = chunk * 256 + tid;   // 0..3071
  const int m = idx >> 9;              // uniform per block
  const int i = idx & 511;

  __shared__ float zs[NM * NDIM];
  __shared__ float vs[256];

  for (int t = tid; t < NM * NDIM; t += 256) zs[t] = z[b * (NM * NDIM) + t];
  __syncthreads();

  float ak0 = bk[i], ak1 = 0.f, av0 = bv[i], av1 = 0.f;
  const float* zr = zs + m * NDIM;
  #pragma unroll 8
  for (int d = 0; d < NDIM; d += 2) {
    const float z0 = zr[d], z1 = zr[d + 1];
    ak0 = fmaf(z0, Wk[d * NINNER + i], ak0);
    ak1 = fmaf(z1, Wk[(d + 1) * NINNER + i], ak1);
    av0 = fmaf(z0, Wv[d * NINNER + i], av0);
    av1 = fmaf(z1, Wv[(d + 1) * NINNER + i], av1);
  }
  kflat[b * NKV + idx] = ak0 + ak1;
  vs[tid] = av0 + av1;
  __syncthreads();

  const int gl = tid >> 6;             // 0..3 (uniform per wave)
  const int c = tid & 63;
  const int g = chunk * 4 + gl;        // 0..47
  const int h = g / 6;
  float a0 = 0.f, a1 = 0.f;
  #pragma unroll 8
  for (int cc = 0; cc < NC; cc += 2) {
    a0 = fmaf(vs[gl * 64 + cc],     Wo[(h * NC + cc) * NC + c],     a0);
    a1 = fmaf(vs[gl * 64 + cc + 1], Wo[(h * NC + cc + 1) * NC + c], a1);
  }
  vw[b * NKV + g * NC + c] = a0 + a1;
}

// ---------------------------------------------------------------------------
// Kernel 2: attention, two-phase, k/VW via wave-uniform (SGPR) pointers.
// grid (32,49), block 256 (4 waves over the same 64 rows).
// Phase 1: wave w -> heads {2w,2w+1}: q streamed from global (coalesced),
//          k rows via uniform float4 loads (s_load-eligible). Softmax ->
//          48 weights/row into LDS aw[48][64].
// Phase 2: wave w -> output channels [16w,16w+16) over all 48 (h,m);
//          VW rows via uniform float4 loads. No cross-wave reduction.
// ---------------------------------------------------------------------------
__global__ __launch_bounds__(256, 4) void attn_kernel(
    const float* __restrict__ x, const float* __restrict__ kflat,
    const float* __restrict__ vw, const float* __restrict__ bo,
    float* __restrict__ out) {
  const int b = blockIdx.x;
  const int lane = threadIdx.x & 63;
  // readfirstlane makes w SGPR-uniform -> k/VW addresses become scalar.
  const int w = __builtin_amdgcn_readfirstlane((int)(threadIdx.x >> 6));
  const int n = blockIdx.y * 64 + lane;   // 0..3135 exact
  const float* __restrict__ xb = x + (size_t)b * CHW;

  __shared__ float aw[NG][64];   // [g][n_local], 12 KB, conflict-free

  // ---- phase 1: dots for heads 2w, 2w+1 ----
  const float* __restrict__ kb = kflat + b * NKV;
  const float* __restrict__ k0 = kb + (2 * w) * (NM * NC);
  const float* __restrict__ k1 = k0 + NM * NC;
  const float* __restrict__ xq = xb + n;   // q[cc] = xq[cc*NHW]

  float d0[NM], d1[NM];
  #pragma unroll
  for (int mm = 0; mm < NM; ++mm) { d0[mm] = 0.f; d1[mm] = 0.f; }

  #pragma unroll 4
  for (int cc = 0; cc < NC; cc += 4) {
    float qv0 = xq[(size_t)(cc + 0) * NHW];
    float qv1 = xq[(size_t)(cc + 1) * NHW];
    float qv2 = xq[(size_t)(cc + 2) * NHW];
    float qv3 = xq[(size_t)(cc + 3) * NHW];
    #pragma unroll
    for (int mm = 0; mm < NM; ++mm) {
      const float4 ka = *(const float4*)(k0 + mm * NC + cc);
      const float4 kc = *(const float4*)(k1 + mm * NC + cc);
      d0[mm] = fmaf(qv0, ka.x, d0[mm]);
      d0[mm] = fmaf(qv1, ka.y, d0[mm]);
      d0[mm] = fmaf(qv2, ka.z, d0[mm]);
      d0[mm] = fmaf(qv3, ka.w, d0[mm]);
      d1[mm] = fmaf(qv0, kc.x, d1[mm]);
      d1[mm] = fmaf(qv1, kc.y, d1[mm]);
      d1[mm] = fmaf(qv2, kc.z, d1[mm]);
      d1[mm] = fmaf(qv3, kc.w, d1[mm]);
    }
  }

  const float scale = 0.125f;  // 64^-0.5
  {
    float mx = d0[0];
    #pragma unroll
    for (int mm = 1; mm < NM; ++mm) mx = fmaxf(mx, d0[mm]);
    float e[NM], s = 0.f;
    #pragma unroll
    for (int mm = 0; mm < NM; ++mm) { e[mm] = __expf((d0[mm] - mx) * scale); s += e[mm]; }
    const float r = 1.0f / s;
    #pragma unroll
    for (int mm = 0; mm < NM; ++mm) aw[(2 * w) * NM + mm][lane] = e[mm] * r;
  }
  {
    float mx = d1[0];
    #pragma unroll
    for (int mm = 1; mm < NM; ++mm) mx = fmaxf(mx, d1[mm]);
    float e[NM], s = 0.f;
    #pragma unroll
    for (int mm = 0; mm < NM; ++mm) { e[mm] = __expf((d1[mm] - mx) * scale); s += e[mm]; }
    const float r = 1.0f / s;
    #pragma unroll
    for (int mm = 0; mm < NM; ++mm) aw[(2 * w + 1) * NM + mm][lane] = e[mm] * r;
  }
  __syncthreads();

  // ---- phase 2: PV for channels [16w,16w+16) over all 48 (h,m) ----
  const int c0 = w * 16;
  const float* __restrict__ vb = vw + b * NKV + c0;  // uniform
  float4 o0 = {0,0,0,0}, o1 = {0,0,0,0}, o2 = {0,0,0,0}, o3 = {0,0,0,0};

  #pragma unroll 4
  for (int g = 0; g < NG; ++g) {
    const float a = aw[g][lane];         // ds_read_b32, conflict-free
    const float* __restrict__ vg = vb + g * NC;
    const float4 v0 = *(const float4*)(vg + 0);
    const float4 v1 = *(const float4*)(vg + 4);
    const float4 v2 = *(const float4*)(vg + 8);
    const float4 v3 = *(const float4*)(vg + 12);
    o0.x = fmaf(a, v0.x, o0.x); o0.y = fmaf(a, v0.y, o0.y);
    o0.z = fmaf(a, v0.z, o0.z); o0.w = fmaf(a, v0.w, o0.w);
    o1.x = fmaf(a, v1.x, o1.x); o1.y = fmaf(a, v1.y, o1.y);
    o1.z = fmaf(a, v1.z, o1.z); o1.w = fmaf(a, v1.w, o1.w);
    o2.x = fmaf(a, v2.x, o2.x); o2.y = fmaf(a, v2.y, o2.y);
    o2.z = fmaf(a, v2.z, o2.z); o2.w = fmaf(a, v2.w, o2.w);
    o3.x = fmaf(a, v3.x, o3.x); o3.y = fmaf(a, v3.y, o3.y);
    o3.z = fmaf(a, v3.z, o3.z); o3.w = fmaf(a, v3.w, o3.w);
  }

  // ---- epilogue: per-lane 4x float4 with bias + residual ----
  const size_t base = (size_t)b * CHW + (size_t)n * NC + c0;
  const float4* __restrict__ xr = (const float4*)(x + base);
  const float4* __restrict__ bo4 = (const float4*)(bo + c0);
  float4* __restrict__ op = (float4*)(out + base);
  {
    float4 xv, bv4, rr;
    xv = xr[0]; bv4 = bo4[0];
    rr.x = o0.x + bv4.x + xv.x; rr.y = o0.y + bv4.y + xv.y;
    rr.z = o0.z + bv4.z + xv.z; rr.w = o0.w + bv4.w + xv.w;
    op[0] = rr;
    xv = xr[1]; bv4 = bo4[1];
    rr.x = o1.x + bv4.x + xv.x; rr.y = o1.y + bv4.y + xv.y;
    rr.z = o1.z + bv4.z + xv.z; rr.w = o1.w + bv4.w + xv.w;
    op[1] = rr;
    xv = xr[2]; bv4 = bo4[2];
    rr.x = o2.x + bv4.x + xv.x; rr.y = o2.y + bv4.y + xv.y;
    rr.z = o2.z + bv4.z + xv.z; rr.w = o2.w + bv4.w + xv.w;
    op[2] = rr;
    xv = xr[3]; bv4 = bo4[3];
    rr.x = o3.x + bv4.x + xv.x; rr.y = o3.y + bv4.y + xv.y;
    rr.z = o3.z + bv4.z + xv.z; rr.w = o3.w + bv4.w + xv.w;
    op[3] = rr;
  }
}

extern "C" void kernel_launch(void* const* d_in, const int* in_sizes, int n_in,
                              void* d_out, int out_size, void* d_ws, size_t ws_size,
                              hipStream_t stream) {
  const float* x  = (const float*)d_in[0];
  const float* z  = (const float*)d_in[1];
  const float* Wk = (const float*)d_in[2];
  const float* bk = (const float*)d_in[3];
  const float* Wv = (const float*)d_in[4];
  const float* bv = (const float*)d_in[5];
  const float* Wo = (const float*)d_in[6];
  const float* bo = (const float*)d_in[7];
  float* out = (float*)d_out;

  float* ws = (float*)d_ws;
  float* kflat = ws;                 // NB*NKV floats
  float* vw    = ws + NB * NKV;      // NB*NKV floats

  kv_proj_kernel<<<dim3(NB, 12), 256, 0, stream>>>(z, Wk, bk, Wv, bv, Wo,
                                                   kflat, vw);
  attn_kernel<<<dim3(NB, 49), 256, 0, stream>>>(x, kflat, vw, bo, out);
}

// Round 7
// 119.709 us; speedup vs baseline: 2.2580x; 1.0724x over previous
//
#include <hip/hip_runtime.h>
#include <math.h>

// Problem constants
#define NB 32
#define NC 64
#define NHW 3136          // 56*56
#define NM 6
#define NDIM 192
#define NHEADS 8
#define NINNER 512        // NHEADS*NC
#define NKV 3072          // NHEADS*NM*NC per batch
#define CHW (NC * NHW)    // 200704
#define NG 48             // NHEADS*NM

// ---------------------------------------------------------------------------
// Kernel 1: kt[b][h][c][m]: k = z@Wk+bk with reshape semantics
//   k[h][mm][cc] = raw_flat[h*384 + mm*64 + cc]  (raw = [m_token][inner])
//   stored transposed as kt[h*384 + cc*6 + mm] for sequential phase-1 reads.
// VW[b][g][c] = sum_cc v_raw[g*64+cc] * Wo[(h*64+cc)*64+c],  g = h*6+m.
// grid (32,12) x 256. z row via block-uniform pointer (m_token = chunk>>1).
// ---------------------------------------------------------------------------
__global__ __launch_bounds__(256) void kv_proj_kernel(
    const float* __restrict__ z, const float* __restrict__ Wk,
    const float* __restrict__ bk, const float* __restrict__ Wv,
    const float* __restrict__ bv, const float* __restrict__ Wo,
    float* __restrict__ kt, float* __restrict__ vw) {
  const int b = blockIdx.x;
  const int chunk = blockIdx.y;
  const int tid = threadIdx.x;
  const int idx = chunk * 256 + tid;   // raw flat 0..3071
  const int mtok = chunk >> 1;         // raw row (uniform per block)
  const int i = idx & 511;             // raw col (inner)

  __shared__ float vs[256];

  const float* __restrict__ zr = z + b * (NM * NDIM) + mtok * NDIM;  // uniform

  float ak0 = bk[i], ak1 = 0.f, av0 = bv[i], av1 = 0.f;
  #pragma unroll 8
  for (int d = 0; d < NDIM; d += 2) {
    const float z0 = zr[d], z1 = zr[d + 1];
    ak0 = fmaf(z0, Wk[d * NINNER + i], ak0);
    ak1 = fmaf(z1, Wk[(d + 1) * NINNER + i], ak1);
    av0 = fmaf(z0, Wv[d * NINNER + i], av0);
    av1 = fmaf(z1, Wv[(d + 1) * NINNER + i], av1);
  }
  // Reshape-view decomposition of the raw flat index idx:
  //   h = idx/384, mm = (idx/64)%6, cc = idx%64  ->  kt[h][cc][mm]
  {
    const int h2 = idx / 384;
    const int mm2 = (idx >> 6) % 6;
    const int cc2 = idx & 63;
    kt[b * NKV + h2 * (NC * NM) + cc2 * NM + mm2] = ak0 + ak1;
  }
  vs[tid] = av0 + av1;
  __syncthreads();

  // VW rows g = chunk*4 .. chunk*4+3; v_raw[g*64+cc] = vs[(g-4*chunk)*64+cc]
  const int gl = tid >> 6;             // 0..3 (uniform per wave)
  const int c = tid & 63;
  const int g = chunk * 4 + gl;        // 0..47
  const int h = g / 6;
  float a0 = 0.f, a1 = 0.f;
  #pragma unroll 8
  for (int cc = 0; cc < NC; cc += 2) {
    a0 = fmaf(vs[gl * 64 + cc],     Wo[(h * NC + cc) * NC + c],     a0);
    a1 = fmaf(vs[gl * 64 + cc + 1], Wo[(h * NC + cc + 1) * NC + c], a1);
  }
  vw[b * NKV + g * NC + c] = a0 + a1;
}

// ---------------------------------------------------------------------------
// Kernel 2: attention. grid (32,49), block 512 = 8 waves over the same 64
// rows. q-tile (64c x 64n) staged to LDS via coalesced float4. Phase 1:
// wave w = head w: d[6] from qs ds_reads x sequential uniform kt reads;
// softmax -> aw[48][64]. Phase 2: wave w -> channels [8w,8w+8) over all 48
// (h,m), VW rows via uniform float4. Residual re-read from GLOBAL x at the
// same flat offset as the output (reshape semantics: out[p] += x[p]).
// ---------------------------------------------------------------------------
__global__ __launch_bounds__(512, 4) void attn_kernel(
    const float* __restrict__ x, const float* __restrict__ kt,
    const float* __restrict__ vw, const float* __restrict__ bo,
    float* __restrict__ out) {
  const int b = blockIdx.x;
  const int lane = threadIdx.x & 63;
  const int w = __builtin_amdgcn_readfirstlane((int)(threadIdx.x >> 6));  // 0..7
  const int n0 = blockIdx.y * 64;
  const int n = n0 + lane;
  const float* __restrict__ xb = x + (size_t)b * CHW;

  __shared__ float qs[NC][64];   // [c][n_local], 16 KB
  __shared__ float aw[NG][64];   // [g][n_local], 12 KB

  // ---- stage q tile: 2 coalesced float4 per thread ----
  {
    const int tc = threadIdx.x >> 4;          // 0..31
    const int tn4 = (threadIdx.x & 15) * 4;   // 0..60
    #pragma unroll
    for (int rep = 0; rep < 2; ++rep) {
      const int c = tc + rep * 32;
      const float4 xv = *(const float4*)(xb + (size_t)c * NHW + n0 + tn4);
      *(float4*)(&qs[c][tn4]) = xv;
    }
  }
  __syncthreads();

  // ---- phase 1: head w. kt head block = 384 sequential floats ----
  const float* __restrict__ kh = kt + b * NKV + w * (NC * NM);  // uniform

  float d[NM];
  #pragma unroll
  for (int mm = 0; mm < NM; ++mm) d[mm] = 0.f;

  #pragma unroll 8
  for (int cc = 0; cc < NC; ++cc) {
    const float qv = qs[cc][lane];       // ds_read_b32, conflict-free
    #pragma unroll
    for (int mm = 0; mm < NM; ++mm)
      d[mm] = fmaf(qv, kh[cc * NM + mm], d[mm]);
  }

  const float scale = 0.125f;  // 64^-0.5
  {
    float mx = d[0];
    #pragma unroll
    for (int mm = 1; mm < NM; ++mm) mx = fmaxf(mx, d[mm]);
    float e[NM], s = 0.f;
    #pragma unroll
    for (int mm = 0; mm < NM; ++mm) { e[mm] = __expf((d[mm] - mx) * scale); s += e[mm]; }
    const float r = 1.0f / s;
    #pragma unroll
    for (int mm = 0; mm < NM; ++mm) aw[w * NM + mm][lane] = e[mm] * r;
  }
  __syncthreads();

  // ---- phase 2: channels [8w, 8w+8) over all 48 (h,m) ----
  const int c0 = w * 8;
  const float* __restrict__ vb = vw + b * NKV + c0;  // uniform
  float4 o0 = {0, 0, 0, 0}, o1 = {0, 0, 0, 0};

  #pragma unroll 4
  for (int g = 0; g < NG; ++g) {
    const float a = aw[g][lane];         // ds_read_b32, conflict-free
    const float4 v0 = *(const float4*)(vb + g * NC);
    const float4 v1 = *(const float4*)(vb + g * NC + 4);
    o0.x = fmaf(a, v0.x, o0.x); o0.y = fmaf(a, v0.y, o0.y);
    o0.z = fmaf(a, v0.z, o0.z); o0.w = fmaf(a, v0.w, o0.w);
    o1.x = fmaf(a, v1.x, o1.x); o1.y = fmaf(a, v1.y, o1.y);
    o1.z = fmaf(a, v1.z, o1.z); o1.w = fmaf(a, v1.w, o1.w);
  }

  // ---- epilogue: bias + residual from global x at the output's flat offset ----
  const size_t base = (size_t)b * CHW + (size_t)n * NC + c0;
  const float4* __restrict__ xr = (const float4*)(x + base);
  const float4 b0 = *(const float4*)(bo + c0);
  const float4 b1 = *(const float4*)(bo + c0 + 4);
  const float4 x0 = xr[0];
  const float4 x1 = xr[1];
  float4 r0, r1;
  r0.x = o0.x + b0.x + x0.x; r0.y = o0.y + b0.y + x0.y;
  r0.z = o0.z + b0.z + x0.z; r0.w = o0.w + b0.w + x0.w;
  r1.x = o1.x + b1.x + x1.x; r1.y = o1.y + b1.y + x1.y;
  r1.z = o1.z + b1.z + x1.z; r1.w = o1.w + b1.w + x1.w;

  float4* __restrict__ op = (float4*)(out + base);
  op[0] = r0;
  op[1] = r1;
}

extern "C" void kernel_launch(void* const* d_in, const int* in_sizes, int n_in,
                              void* d_out, int out_size, void* d_ws, size_t ws_size,
                              hipStream_t stream) {
  const float* x  = (const float*)d_in[0];
  const float* z  = (const float*)d_in[1];
  const float* Wk = (const float*)d_in[2];
  const float* bk = (const float*)d_in[3];
  const float* Wv = (const float*)d_in[4];
  const float* bv = (const float*)d_in[5];
  const float* Wo = (const float*)d_in[6];
  const float* bo = (const float*)d_in[7];
  float* out = (float*)d_out;

  float* ws = (float*)d_ws;
  float* kt = ws;                    // NB*NKV floats, [b][h][c][m]
  float* vw = ws + NB * NKV;         // NB*NKV floats, [b][g][c]

  kv_proj_kernel<<<dim3(NB, 12), 256, 0, stream>>>(z, Wk, bk, Wv, bv, Wo,
                                                   kt, vw);
  attn_kernel<<<dim3(NB, 49), 512, 0, stream>>>(x, kt, vw, bo, out);
}